// Round 3
// baseline (358.827 us; speedup 1.0000x reference)
//
#include <hip/hip_runtime.h>
#include <hip/hip_bf16.h>
#include <stdint.h>

// Problem constants: B=4, S=8192, IN=1024, OUT=1024
#define M_TOT  32768
#define K_DIM  1024
#define N_DIM  1024
#define NGRP   256          // 128-row mask groups

typedef short bf16x8 __attribute__((ext_vector_type(8)));   // 8 bf16 = 4 VGPRs
typedef float f32x4  __attribute__((ext_vector_type(4)));

#define AS1(p) ((__attribute__((address_space(1))) void*)(p))
#define AS3(p) ((__attribute__((address_space(3))) void*)(p))

__device__ __forceinline__ uint32_t packbf2(float a, float b) {
    __hip_bfloat162 h = __float22bfloat162_rn(make_float2(a, b));
    union { __hip_bfloat162 h; uint32_t u; } cvt;
    cvt.h = h;
    return cvt.u;
}

// ---------- prep: W fp32->bf16 + per-group mask bits & counts (no atomics) ----------
__global__ __launch_bounds__(256) void prep_kernel(
        const float* __restrict__ wv, const float* __restrict__ wt,
        const int*   __restrict__ mask,
        ushort* __restrict__ dv, ushort* __restrict__ dt,
        uint32_t* __restrict__ mbits, int* __restrict__ gcnt) {
    const int b = blockIdx.x, tid = threadIdx.x;
    __shared__ int scnt[2];
    if (tid < 128) {                        // waves 0,1 fully active
        int v = mask[b * 128 + tid] != 0;
        unsigned long long bal = __ballot(v);
        int wv_ = tid >> 6;
        if ((tid & 63) == 0) {
            mbits[b * 4 + wv_ * 2 + 0] = (uint32_t)bal;
            mbits[b * 4 + wv_ * 2 + 1] = (uint32_t)(bal >> 32);
            scnt[wv_] = __popcll(bal);
        }
    }
    __syncthreads();
    if (tid == 0) gcnt[b] = scnt[0] + scnt[1];

    // W cvt: 2048 float4 per block (blocks 0..127 -> Wv, 128..255 -> Wt)
    const float* src; ushort* dst; int base;
    if (b < 128) { src = wv; dst = dv; base = b * 2048; }
    else         { src = wt; dst = dt; base = (b - 128) * 2048; }
#pragma unroll
    for (int j = 0; j < 8; ++j) {
        int idx = base + j * 256 + tid;
        float4 a = ((const float4*)src)[idx];
        uint2 p;
        p.x = packbf2(a.x, a.y);
        p.y = packbf2(a.z, a.w);
        *(uint2*)(dst + (size_t)idx * 4) = p;
    }
}

// ---------- fused GEMM: per-block deterministic row partition + in-staging cvt ----------
// Each block: 128 rows of one class (pure W_v or W_t), 128 cols, K=1024.
// A staged fp32->bf16 through VGPRs (x is L3-warm); B via global_load_lds w=16.
__global__ __launch_bounds__(256) void gemm_kernel(
        const float*    __restrict__ x,
        const ushort*   __restrict__ Wv,
        const ushort*   __restrict__ Wt,
        const uint32_t* __restrict__ mbits,
        const int*      __restrict__ gcnt,
        float*          __restrict__ out) {
    __shared__ ushort sA[128 * 64];   // 16 KB
    __shared__ ushort sB[128 * 64];   // 16 KB
    __shared__ int s_pref[257];
    __shared__ int s_row[128];
    __shared__ int wsum[4];

    const int tid  = threadIdx.x;
    const int lane = tid & 63;
    const int w    = tid >> 6;

    // ---- prefix scan of the 256 group visual-counts ----
    {
        int c = (tid < NGRP) ? gcnt[tid] : 0;
        int incl = c;
#pragma unroll
        for (int d = 1; d < 64; d <<= 1) {
            int y = __shfl_up(incl, d);
            if (lane >= d) incl += y;
        }
        if (lane == 63) wsum[w] = incl;
        __syncthreads();
        int excl = 0;
#pragma unroll
        for (int i = 0; i < 4; ++i) if (i < w) excl += wsum[i];
        if (tid < NGRP) s_pref[tid + 1] = excl + incl;
        if (tid == 0) s_pref[0] = 0;
        __syncthreads();
    }
    const int Nv  = s_pref[256];
    const int Nt  = M_TOT - Nv;
    const int NBv = (Nv + 127) >> 7;
    const int NBt = (Nt + 127) >> 7;

    // XCD-sticky swizzle: 8 bn-blocks of one bm share blockIdx%8
    const int kx = blockIdx.x & 7;
    const int bn = (blockIdx.x >> 3) & 7;
    const int gk = blockIdx.x >> 6;
    const int bm = gk * 8 + kx;
    if (bm >= NBv + NBt) return;          // uniform whole-block exit

    const bool vis = (bm < NBv);
    const int  r0  = vis ? bm * 128 : (bm - NBv) * 128;
    const int  cap = vis ? Nv : Nt;

    // ---- row selection: thread t<128 resolves global rank r0+t -> row index ----
    if (tid < 128) {
        int r = r0 + tid;
        int row = -1;
        if (r < cap) {
            int g = 0;
#pragma unroll
            for (int st = 128; st >= 1; st >>= 1) {
                int ng = g + st;
                if (ng <= 255) {
                    int P = vis ? s_pref[ng] : ng * 128 - s_pref[ng];
                    if (P <= r) g = ng;
                }
            }
            int P = vis ? s_pref[g] : g * 128 - s_pref[g];
            int s = r - P;
            int4 q = *(const int4*)(mbits + g * 4);
            uint32_t wd[4] = {(uint32_t)q.x, (uint32_t)q.y, (uint32_t)q.z, (uint32_t)q.w};
            if (!vis) { wd[0] = ~wd[0]; wd[1] = ~wd[1]; wd[2] = ~wd[2]; wd[3] = ~wd[3]; }
            int wsel = 0;
#pragma unroll
            for (int j = 0; j < 3; ++j) {
                int c = __popc(wd[wsel]);
                if (s >= c) { s -= c; wsel++; }
            }
            uint32_t word = wd[wsel];
            int pos = 0;
#pragma unroll
            for (int width = 16; width >= 1; width >>= 1) {
                int c = __popc((word >> pos) & ((1u << width) - 1u));
                if (s >= c) { s -= c; pos += width; }
            }
            row = g * 128 + wsel * 32 + pos;
        }
        s_row[tid] = row;
    }
    __syncthreads();

    const ushort* W  = vis ? Wv : Wt;
    const int     n0 = bn * 128;

    // ---- A staging assignment: thread (tr=tid>>3, kc=tid&7), rows i*32+tr ----
    const int kc = tid & 7;
    const int tr = tid >> 3;
    const float* xp[4];
    uint32_t aw[4];
#pragma unroll
    for (int i = 0; i < 4; ++i) {
        int m  = i * 32 + tr;
        int rr = s_row[m];
        if (rr < 0) rr = 0;                 // sentinel: safe addr, store masked later
        xp[i] = x + (size_t)rr * K_DIM + kc * 8;
        aw[i] = (uint32_t)((m * 8 + (kc ^ (m & 7))) * 16);
    }
    // B DMA: LDS chunk p = r*256+tid holds W row n=p>>3, chunk (tid&7)^(n&7)
    const int kcb = (tid & 7) ^ (tr & 7);
    const ushort* wp[4];
#pragma unroll
    for (int r = 0; r < 4; ++r)
        wp[r] = W + (size_t)(n0 + r * 32 + tr) * K_DIM + kcb * 8;

    // fragment read offsets (bytes), 16B-chunk XOR swizzle
    const int ml   = lane & 15;
    const int quad = lane >> 4;
    const int wm = (w & 1) * 64;
    const int wn = (w >> 1) * 64;
    uint32_t aoff[2][4], boff[2][4];
#pragma unroll
    for (int ks = 0; ks < 2; ++ks) {
        int kxr = (ks * 4 + quad) ^ (ml & 7);
#pragma unroll
        for (int t = 0; t < 4; ++t) {
            aoff[ks][t] = (uint32_t)(((wm + t * 16 + ml) * 8 + kxr) * 16);
            boff[ks][t] = (uint32_t)(((wn + t * 16 + ml) * 8 + kxr) * 16);
        }
    }

    f32x4 acc[4][4];
#pragma unroll
    for (int i = 0; i < 4; ++i)
#pragma unroll
        for (int j = 0; j < 4; ++j) {
            f32x4 z = {0.f, 0.f, 0.f, 0.f};
            acc[i][j] = z;
        }

    char* sAb = (char*)sA;
    char* sBb = (char*)sB;

    for (int kt = 0; kt < 16; ++kt) {
        const int k0 = kt * 64;
        // B first: DMA overlaps the A VGPR round-trip
#pragma unroll
        for (int r = 0; r < 4; ++r) {
            char* lb = sBb + (size_t)(r * 256 + w * 64) * 16;   // wave-uniform base
            __builtin_amdgcn_global_load_lds(AS1(wp[r] + k0), AS3(lb), 16, 0, 0);
        }
        // A: gathered fp32 load -> bf16 pack -> LDS (swizzled ds_write_b128)
#pragma unroll
        for (int i = 0; i < 4; ++i) {
            const float4* p = (const float4*)(xp[i] + k0);
            float4 a = p[0];
            float4 b = p[1];
            uint4 pk;
            pk.x = packbf2(a.x, a.y);
            pk.y = packbf2(a.z, a.w);
            pk.z = packbf2(b.x, b.y);
            pk.w = packbf2(b.z, b.w);
            *(uint4*)(sAb + aw[i]) = pk;
        }
        __syncthreads();
#pragma unroll
        for (int ks = 0; ks < 2; ++ks) {
            bf16x8 af[4], bf[4];
#pragma unroll
            for (int t = 0; t < 4; ++t) af[t] = *(const bf16x8*)(sAb + aoff[ks][t]);
#pragma unroll
            for (int t = 0; t < 4; ++t) bf[t] = *(const bf16x8*)(sBb + boff[ks][t]);
#pragma unroll
            for (int tm = 0; tm < 4; ++tm)
#pragma unroll
                for (int tn = 0; tn < 4; ++tn)
                    acc[tm][tn] = __builtin_amdgcn_mfma_f32_16x16x32_bf16(
                        af[tm], bf[tn], acc[tm][tn], 0, 0, 0);
        }
        __syncthreads();
    }

    // ---- epilogue: scatter rows (C/D: col=lane&15, row=quad*4+reg), sorted rows ----
#pragma unroll
    for (int tm = 0; tm < 4; ++tm) {
        const int rb = wm + tm * 16 + quad * 4;
        int sr0 = s_row[rb + 0];
        int sr1 = s_row[rb + 1];
        int sr2 = s_row[rb + 2];
        int sr3 = s_row[rb + 3];
#pragma unroll
        for (int tn = 0; tn < 4; ++tn) {
            const int col = n0 + wn + tn * 16 + ml;
            if (sr0 >= 0) out[(size_t)sr0 * N_DIM + col] = acc[tm][tn][0];
            if (sr1 >= 0) out[(size_t)sr1 * N_DIM + col] = acc[tm][tn][1];
            if (sr2 >= 0) out[(size_t)sr2 * N_DIM + col] = acc[tm][tn][2];
            if (sr3 >= 0) out[(size_t)sr3 * N_DIM + col] = acc[tm][tn][3];
        }
    }
}

// ws layout (total ~4.2 MB — keep ws small: harness poisons all of it each replay):
//   [0, 2MB)       W_v bf16
//   [2MB, 4MB)     W_t bf16
//   [4MB, +4KB)    mbits  (256 groups x 4 uint32)
//   [..,  +1KB)    gcnt   (256 int)
extern "C" void kernel_launch(void* const* d_in, const int* in_sizes, int n_in,
                              void* d_out, int out_size, void* d_ws, size_t ws_size,
                              hipStream_t stream) {
    const float* x    = (const float*)d_in[0];
    const int*   mask = (const int*)d_in[1];
    const float* Wv   = (const float*)d_in[2];
    const float* Wt   = (const float*)d_in[3];
    float* out = (float*)d_out;

    char* ws = (char*)d_ws;
    ushort*   dWv   = (ushort*)(ws);
    ushort*   dWt   = (ushort*)(ws + 2097152);
    uint32_t* mbits = (uint32_t*)(ws + 4194304);
    int*      gcnt  = (int*)(ws + 4194304 + 4096);

    prep_kernel<<<256, 256, 0, stream>>>(Wv, Wt, mask, dWv, dWt, mbits, gcnt);
    // grid: bm = gk*8 + (blockIdx&7) must reach 257 -> gk up to 32 -> 33*64 blocks
    gemm_kernel<<<33 * 64, 256, 0, stream>>>(x, dWv, dWt, mbits, gcnt, out);
}